// Round 16
// baseline (31.998 us; speedup 1.0000x reference)
//
#include <hip/hip_runtime.h>

// Chamfer distance — fused per-block design, no partial matrices, no atomics.
// pts = img_render_points[0]      : 4096 x 2 f32 (slice 0)
// refs = ref_catheter_skeleton[1] : 32768 x 2 f32 (last slice; flip is neutral)
//
// ||p-r||^2 = ||p||^2 + (||r||^2 - 2 p.r);  min over sq, one sqrt per point.
// Block b owns pts [b*16,+16) (phase A: min over ALL refs, refs split across
// 512 threads) and refs [b*128,+128) (phase B: wave w owns 16 refs, its 64
// lanes split ALL pts). Mins resolve in-register -> wave shfl_xor -> tiny LDS.
// One partial sum per block; 1-block sum kernel stores out. Deterministic.

typedef float v2f __attribute__((ext_vector_type(2)));

constexpr int N_PTS = 4096;
constexpr int M_REF = 32768;

__device__ __forceinline__ v2f pk_fma(v2f a, v2f b, v2f c) {
    v2f d;
    asm("v_pk_fma_f32 %0, %1, %2, %3" : "=v"(d) : "v"(a), "v"(b), "v"(c));
    return d;
}
__device__ __forceinline__ v2f pk_mul(v2f a, v2f b) {
    v2f d;
    asm("v_pk_mul_f32 %0, %1, %2" : "=v"(d) : "v"(a), "v"(b));
    return d;
}

// ---------------- Kernel 1: fused chamfer, 256 blocks x 512 threads --------
__global__ __launch_bounds__(512) void chamfer_fused(
    const float2* __restrict__ pts, const float2* __restrict__ refs,
    float* __restrict__ partial)   // [256]
{
    __shared__ float redA[128];    // 8 waves x 16 pt-mins
    __shared__ float redB[24];     // 16 pt-dists + 8 wave ref-dist sums
    const int tid = threadIdx.x, b = blockIdx.x;
    const int lane = tid & 63, wave = tid >> 6;
    const float4* pts4  = (const float4*)pts;    // (x0,y0,x1,y1) pairs
    const float4* refs4 = (const float4*)refs;

    // ---- Phase A: block's 16 pts vs ALL refs (refs split across threads) --
    v2f px2[16], py2[16];
    float mn[16];
    #pragma unroll
    for (int q = 0; q < 8; ++q) {
        const float4 o = pts4[b * 8 + q];        // uniform -> scalar loads
        px2[2*q]   = (v2f){-2.f*o.x, -2.f*o.x};
        py2[2*q]   = (v2f){-2.f*o.y, -2.f*o.y};
        px2[2*q+1] = (v2f){-2.f*o.z, -2.f*o.z};
        py2[2*q+1] = (v2f){-2.f*o.w, -2.f*o.w};
    }
    #pragma unroll
    for (int k = 0; k < 16; ++k) mn[k] = 3.0e38f;

    #pragma unroll 4
    for (int i = 0; i < 32; ++i) {               // 64 refs/thread, coalesced
        const float4 rr = refs4[tid + 512 * i];  // L2-resident stream
        const v2f rx2 = (v2f){rr.x, rr.z};
        const v2f ry2 = (v2f){rr.y, rr.w};
        const v2f rz2 = pk_fma(rx2, rx2, pk_mul(ry2, ry2));   // (||r0||²,||r1||²)
        #pragma unroll
        for (int k = 0; k < 16; ++k) {
            const v2f d2 = pk_fma(px2[k], rx2, pk_fma(py2[k], ry2, rz2));
            mn[k] = fminf(fminf(mn[k], d2.x), d2.y);          // v_min3_f32
        }
    }
    #pragma unroll
    for (int k = 0; k < 16; ++k) {
        #pragma unroll
        for (int m = 1; m < 64; m <<= 1)
            mn[k] = fminf(mn[k], __shfl_xor(mn[k], m, 64));   // wave min
    }
    if (lane == 0) {
        #pragma unroll
        for (int k = 0; k < 16; ++k) redA[wave * 16 + k] = mn[k];
    }
    __syncthreads();
    if (tid < 16) {                              // cross-wave min + sqrt
        float m = redA[tid];
        #pragma unroll
        for (int w = 1; w < 8; ++w) m = fminf(m, redA[w * 16 + tid]);
        const float2 p = pts[b * 16 + tid];
        redB[tid] = sqrtf(fmaxf(m + fmaf(p.x, p.x, p.y * p.y), 1e-12f));
    }

    // ---- Phase B: block's 128 refs vs ALL pts (wave w owns 16 refs) -------
    v2f rxs[16], rys[16];
    float n2r[16];
    #pragma unroll
    for (int q = 0; q < 8; ++q) {
        const float4 o = refs4[b * 64 + wave * 8 + q];   // wave-uniform
        rxs[2*q]   = (v2f){-2.f*o.x, -2.f*o.x};
        rys[2*q]   = (v2f){-2.f*o.y, -2.f*o.y};
        n2r[2*q]   = fmaf(o.x, o.x, o.y * o.y);
        rxs[2*q+1] = (v2f){-2.f*o.z, -2.f*o.z};
        rys[2*q+1] = (v2f){-2.f*o.w, -2.f*o.w};
        n2r[2*q+1] = fmaf(o.z, o.z, o.w * o.w);
    }
    #pragma unroll
    for (int k = 0; k < 16; ++k) mn[k] = 3.0e38f;

    #pragma unroll 4
    for (int i = 0; i < 32; ++i) {               // 64 pts/lane, coalesced/wave
        const float4 pp = pts4[lane + 64 * i];
        const v2f pxx = (v2f){pp.x, pp.z};
        const v2f pyy = (v2f){pp.y, pp.w};
        const v2f pzz = pk_fma(pxx, pxx, pk_mul(pyy, pyy));   // (||p0||²,||p1||²)
        #pragma unroll
        for (int k = 0; k < 16; ++k) {
            const v2f d2 = pk_fma(rxs[k], pxx, pk_fma(rys[k], pyy, pzz));
            mn[k] = fminf(fminf(mn[k], d2.x), d2.y);
        }
    }
    #pragma unroll
    for (int k = 0; k < 16; ++k) {
        #pragma unroll
        for (int m = 1; m < 64; m <<= 1)
            mn[k] = fminf(mn[k], __shfl_xor(mn[k], m, 64));   // full min (64-way pt split)
    }
    if (lane == 0) {                             // 16 ref-dists, fixed order
        float s = 0.f;
        #pragma unroll
        for (int k = 0; k < 16; ++k)
            s += sqrtf(fmaxf(mn[k] + n2r[k], 1e-12f));
        redB[16 + wave] = s;
    }
    __syncthreads();
    if (tid == 0) {                              // block partial, fixed order
        float t = 0.f;
        #pragma unroll
        for (int k = 0; k < 24; ++k) t += redB[k];
        partial[b] = t;                          // plain store, written once
    }
}

// ---------------- Kernel 2: sum 256 partials (plain store) -----------------
__global__ __launch_bounds__(256) void chamfer_sum(
    const float* __restrict__ partial, float* __restrict__ out)
{
    __shared__ float ssum[4];
    const int tid = threadIdx.x;
    float d = partial[tid];
    #pragma unroll
    for (int off = 32; off > 0; off >>= 1) d += __shfl_down(d, off, 64);
    const int lane = tid & 63, wave = tid >> 6;
    if (lane == 0) ssum[wave] = d;
    __syncthreads();
    if (tid == 0) out[0] = ssum[0] + ssum[1] + ssum[2] + ssum[3];
}

extern "C" void kernel_launch(void* const* d_in, const int* in_sizes, int n_in,
                              void* d_out, int out_size, void* d_ws, size_t ws_size,
                              hipStream_t stream) {
    const float2* pts  = (const float2*)d_in[0];            // circle 0 (offset 0)
    const float2* refs = ((const float2*)d_in[1]) + M_REF;  // last (=2nd) skeleton slice

    float* partial = (float*)d_ws;                          // [256] floats
    float* out = (float*)d_out;

    chamfer_fused<<<256, 512, 0, stream>>>(pts, refs, partial);
    chamfer_sum  <<<1, 256, 0, stream>>>(partial, out);
}

// Round 17
// 30.415 us; speedup vs baseline: 1.0520x; 1.0520x over previous
//
#include <hip/hip_runtime.h>

// Chamfer distance — fused, phase-interleaved, no partial matrices, no atomics.
// pts = img_render_points[0]      : 4096 x 2 f32 (slice 0)
// refs = ref_catheter_skeleton[1] : 32768 x 2 f32 (last slice; flip is neutral)
//
// ||p-r||^2 = ||p||^2 + (||r||^2 - 2 p.r);  min over sq, one sqrt per point.
// 512 blocks x 512 threads, 2 blocks/CU (launch_bounds(512,4) -> 4 waves/SIMD).
// Phase A: block owns 8 pts; ALL refs split across 512 threads (32 f4 each).
// Phase B: wave owns 8 refs; its 64 lanes split ALL pts (32 f4 each).
// Both phases interleaved in ONE 32-iteration loop: 2 independent load
// streams + 2 independent packed-FMA chains per iteration (ILP x2 on top of
// TLP x2 vs round 16 — that kernel measured VALUBusy 29%, Occ 18.6%).

typedef float v2f __attribute__((ext_vector_type(2)));

constexpr int N_PTS = 4096;
constexpr int M_REF = 32768;

__device__ __forceinline__ v2f pk_fma(v2f a, v2f b, v2f c) {
    v2f d;
    asm("v_pk_fma_f32 %0, %1, %2, %3" : "=v"(d) : "v"(a), "v"(b), "v"(c));
    return d;
}
__device__ __forceinline__ v2f pk_mul(v2f a, v2f b) {
    v2f d;
    asm("v_pk_mul_f32 %0, %1, %2" : "=v"(d) : "v"(a), "v"(b));
    return d;
}

// ---------------- Kernel 1: fused chamfer, 512 blocks x 512 threads --------
__global__ __launch_bounds__(512, 4) void chamfer_fused(
    const float2* __restrict__ pts, const float2* __restrict__ refs,
    float* __restrict__ partial)   // [512]
{
    __shared__ float redA[64];     // 8 waves x 8 pt-mins
    __shared__ float redB[16];     // 8 pt-dists + 8 wave ref-dist sums
    const int tid = threadIdx.x, b = blockIdx.x;
    const int lane = tid & 63, wave = tid >> 6;
    const float4* pts4  = (const float4*)pts;    // (x0,y0,x1,y1) pairs
    const float4* refs4 = (const float4*)refs;

    // Phase-A state: 8 own pts (block-uniform), -2 folded in.
    v2f pxA[8], pyA[8]; float mnA[8];
    #pragma unroll
    for (int q = 0; q < 4; ++q) {
        const float4 o = pts4[b * 4 + q];
        pxA[2*q]   = (v2f){-2.f*o.x, -2.f*o.x};
        pyA[2*q]   = (v2f){-2.f*o.y, -2.f*o.y};
        pxA[2*q+1] = (v2f){-2.f*o.z, -2.f*o.z};
        pyA[2*q+1] = (v2f){-2.f*o.w, -2.f*o.w};
    }
    // Phase-B state: 8 own refs (wave-uniform), -2 folded in, ||r||^2 kept.
    v2f rxB[8], ryB[8]; float n2B[8], mnB[8];
    #pragma unroll
    for (int q = 0; q < 4; ++q) {
        const float4 o = refs4[b * 32 + wave * 4 + q];
        rxB[2*q]   = (v2f){-2.f*o.x, -2.f*o.x};
        ryB[2*q]   = (v2f){-2.f*o.y, -2.f*o.y};
        n2B[2*q]   = fmaf(o.x, o.x, o.y * o.y);
        rxB[2*q+1] = (v2f){-2.f*o.z, -2.f*o.z};
        ryB[2*q+1] = (v2f){-2.f*o.w, -2.f*o.w};
        n2B[2*q+1] = fmaf(o.z, o.z, o.w * o.w);
    }
    #pragma unroll
    for (int k = 0; k < 8; ++k) { mnA[k] = 3.0e38f; mnB[k] = 3.0e38f; }

    // Interleaved main loop: 32 iterations, 2 independent streams.
    #pragma unroll 2
    for (int i = 0; i < 32; ++i) {
        const float4 rr = refs4[tid  + 512 * i];   // A: coalesced ref stream
        const float4 pp = pts4 [lane +  64 * i];   // B: per-wave pt stream
        // ---- A math ----
        const v2f rx2 = (v2f){rr.x, rr.z};
        const v2f ry2 = (v2f){rr.y, rr.w};
        const v2f rz2 = pk_fma(rx2, rx2, pk_mul(ry2, ry2));
        #pragma unroll
        for (int k = 0; k < 8; ++k) {
            const v2f d2 = pk_fma(pxA[k], rx2, pk_fma(pyA[k], ry2, rz2));
            mnA[k] = fminf(fminf(mnA[k], d2.x), d2.y);   // v_min3_f32
        }
        // ---- B math ----
        const v2f px2 = (v2f){pp.x, pp.z};
        const v2f py2 = (v2f){pp.y, pp.w};
        const v2f pz2 = pk_fma(px2, px2, pk_mul(py2, py2));
        #pragma unroll
        for (int k = 0; k < 8; ++k) {
            const v2f d2 = pk_fma(rxB[k], px2, pk_fma(ryB[k], py2, pz2));
            mnB[k] = fminf(fminf(mnB[k], d2.x), d2.y);
        }
    }

    // ---- Phase A reduce: wave min -> LDS ----
    #pragma unroll
    for (int k = 0; k < 8; ++k) {
        #pragma unroll
        for (int m = 1; m < 64; m <<= 1)
            mnA[k] = fminf(mnA[k], __shfl_xor(mnA[k], m, 64));
    }
    if (lane == 0) {
        #pragma unroll
        for (int k = 0; k < 8; ++k) redA[wave * 8 + k] = mnA[k];
    }
    // ---- Phase B reduce: wave min is complete (lanes covered all pts) ----
    #pragma unroll
    for (int k = 0; k < 8; ++k) {
        #pragma unroll
        for (int m = 1; m < 64; m <<= 1)
            mnB[k] = fminf(mnB[k], __shfl_xor(mnB[k], m, 64));
    }
    if (lane == 0) {
        float s = 0.f;
        #pragma unroll
        for (int k = 0; k < 8; ++k)
            s += sqrtf(fmaxf(mnB[k] + n2B[k], 1e-12f));
        redB[8 + wave] = s;
    }
    __syncthreads();
    if (tid < 8) {                               // cross-wave fold for A + sqrt
        float m = redA[tid];
        #pragma unroll
        for (int w = 1; w < 8; ++w) m = fminf(m, redA[w * 8 + tid]);
        const float2 p = pts[b * 8 + tid];
        redB[tid] = sqrtf(fmaxf(m + fmaf(p.x, p.x, p.y * p.y), 1e-12f));
    }
    __syncthreads();
    if (tid == 0) {                              // block partial, fixed order
        float t = 0.f;
        #pragma unroll
        for (int k = 0; k < 16; ++k) t += redB[k];
        partial[b] = t;                          // plain store, written once
    }
}

// ---------------- Kernel 2: sum 512 partials (plain store) -----------------
__global__ __launch_bounds__(512) void chamfer_sum(
    const float* __restrict__ partial, float* __restrict__ out)
{
    __shared__ float ssum[8];
    const int tid = threadIdx.x;
    float d = partial[tid];
    #pragma unroll
    for (int off = 32; off > 0; off >>= 1) d += __shfl_down(d, off, 64);
    const int lane = tid & 63, wave = tid >> 6;
    if (lane == 0) ssum[wave] = d;
    __syncthreads();
    if (tid == 0) {
        float t = 0.f;
        #pragma unroll
        for (int w = 0; w < 8; ++w) t += ssum[w];
        out[0] = t;
    }
}

extern "C" void kernel_launch(void* const* d_in, const int* in_sizes, int n_in,
                              void* d_out, int out_size, void* d_ws, size_t ws_size,
                              hipStream_t stream) {
    const float2* pts  = (const float2*)d_in[0];            // circle 0 (offset 0)
    const float2* refs = ((const float2*)d_in[1]) + M_REF;  // last (=2nd) skeleton slice

    float* partial = (float*)d_ws;                          // [512] floats
    float* out = (float*)d_out;

    chamfer_fused<<<512, 512, 0, stream>>>(pts, refs, partial);
    chamfer_sum  <<<1, 512, 0, stream>>>(partial, out);
}

// Round 18
// 29.505 us; speedup vs baseline: 1.0845x; 1.0308x over previous
//
#include <hip/hip_runtime.h>

// Chamfer distance — fused, phase-interleaved, batched-MLP loads.
// pts = img_render_points[0]      : 4096 x 2 f32 (slice 0)
// refs = ref_catheter_skeleton[1] : 32768 x 2 f32 (last slice; flip is neutral)
//
// ||p-r||^2 = ||p||^2 + (||r||^2 - 2 p.r);  min over sq, one sqrt per point.
// 256 blocks x 512 threads (1 block/CU, 2 waves/SIMD, VGPR ~210).
// Phase A: block owns 16 pts; ALL refs split across 512 threads.
// Phase B: wave owns 16 refs; its 64 lanes split ALL pts.
// Main loop: 8 outer steps; each loads 4 iterations of BOTH streams
// (8 independent global_load_dwordx4 in flight) then runs ~1300 cyc of FMA —
// amortizes L2 latency 8x (R16 measured VALUBusy 29%: per-iter vmcnt(0)
// exposed the full L2 round trip each iteration).

typedef float v2f __attribute__((ext_vector_type(2)));

constexpr int N_PTS = 4096;
constexpr int M_REF = 32768;

__device__ __forceinline__ v2f pk_fma(v2f a, v2f b, v2f c) {
    v2f d;
    asm("v_pk_fma_f32 %0, %1, %2, %3" : "=v"(d) : "v"(a), "v"(b), "v"(c));
    return d;
}
__device__ __forceinline__ v2f pk_mul(v2f a, v2f b) {
    v2f d;
    asm("v_pk_mul_f32 %0, %1, %2" : "=v"(d) : "v"(a), "v"(b));
    return d;
}

// ---------------- Kernel 1: fused chamfer, 256 blocks x 512 threads --------
__global__ __launch_bounds__(512) void chamfer_fused(
    const float2* __restrict__ pts, const float2* __restrict__ refs,
    float* __restrict__ partial)   // [256]
{
    __shared__ float redA[128];    // 8 waves x 16 pt-mins
    __shared__ float redB[24];     // 16 pt-dists + 8 wave ref-dist sums
    const int tid = threadIdx.x, b = blockIdx.x;
    const int lane = tid & 63, wave = tid >> 6;
    const float4* pts4  = (const float4*)pts;    // (x0,y0,x1,y1) pairs
    const float4* refs4 = (const float4*)refs;

    // Phase-A state: 16 own pts (block-uniform), -2 folded in.
    v2f pxA[16], pyA[16]; float mnA[16];
    #pragma unroll
    for (int q = 0; q < 8; ++q) {
        const float4 o = pts4[b * 8 + q];
        pxA[2*q]   = (v2f){-2.f*o.x, -2.f*o.x};
        pyA[2*q]   = (v2f){-2.f*o.y, -2.f*o.y};
        pxA[2*q+1] = (v2f){-2.f*o.z, -2.f*o.z};
        pyA[2*q+1] = (v2f){-2.f*o.w, -2.f*o.w};
    }
    // Phase-B state: 16 own refs (wave-uniform), -2 folded in.
    v2f rxB[16], ryB[16]; float mnB[16];
    #pragma unroll
    for (int q = 0; q < 8; ++q) {
        const float4 o = refs4[b * 64 + wave * 8 + q];
        rxB[2*q]   = (v2f){-2.f*o.x, -2.f*o.x};
        ryB[2*q]   = (v2f){-2.f*o.y, -2.f*o.y};
        rxB[2*q+1] = (v2f){-2.f*o.z, -2.f*o.z};
        ryB[2*q+1] = (v2f){-2.f*o.w, -2.f*o.w};
    }
    #pragma unroll
    for (int k = 0; k < 16; ++k) { mnA[k] = 3.0e38f; mnB[k] = 3.0e38f; }

    // Main loop: 8 outers x 4 inners; 8 loads in flight per outer.
    for (int o = 0; o < 8; ++o) {
        float4 rr[4], pp[4];
        #pragma unroll
        for (int u = 0; u < 4; ++u) {
            rr[u] = refs4[tid  + 512 * (4 * o + u)];   // A: coalesced ref stream
            pp[u] = pts4 [lane +  64 * (4 * o + u)];   // B: per-wave pt stream
        }
        #pragma unroll
        for (int u = 0; u < 4; ++u) {
            // ---- A math ----
            const v2f rx2 = (v2f){rr[u].x, rr[u].z};
            const v2f ry2 = (v2f){rr[u].y, rr[u].w};
            const v2f rz2 = pk_fma(rx2, rx2, pk_mul(ry2, ry2));
            #pragma unroll
            for (int k = 0; k < 16; ++k) {
                const v2f d2 = pk_fma(pxA[k], rx2, pk_fma(pyA[k], ry2, rz2));
                mnA[k] = fminf(fminf(mnA[k], d2.x), d2.y);   // v_min3_f32
            }
            // ---- B math ----
            const v2f px2 = (v2f){pp[u].x, pp[u].z};
            const v2f py2 = (v2f){pp[u].y, pp[u].w};
            const v2f pz2 = pk_fma(px2, px2, pk_mul(py2, py2));
            #pragma unroll
            for (int k = 0; k < 16; ++k) {
                const v2f d2 = pk_fma(rxB[k], px2, pk_fma(ryB[k], py2, pz2));
                mnB[k] = fminf(fminf(mnB[k], d2.x), d2.y);
            }
        }
    }

    // ---- Phase A reduce: wave min -> LDS ----
    #pragma unroll
    for (int k = 0; k < 16; ++k) {
        #pragma unroll
        for (int m = 1; m < 64; m <<= 1)
            mnA[k] = fminf(mnA[k], __shfl_xor(mnA[k], m, 64));
    }
    if (lane == 0) {
        #pragma unroll
        for (int k = 0; k < 16; ++k) redA[wave * 16 + k] = mnA[k];
    }
    // ---- Phase B reduce: wave min is complete (lanes covered all pts) ----
    #pragma unroll
    for (int k = 0; k < 16; ++k) {
        #pragma unroll
        for (int m = 1; m < 64; m <<= 1)
            mnB[k] = fminf(mnB[k], __shfl_xor(mnB[k], m, 64));
    }
    if (lane == 0) {
        float s = 0.f;
        #pragma unroll
        for (int k = 0; k < 16; ++k) {
            // ||r||^2 from the splatted -2x,-2y: (rx^2+ry^2)/4
            const float n2 = 0.25f * fmaf(rxB[k].x, rxB[k].x, ryB[k].x * ryB[k].x);
            s += sqrtf(fmaxf(mnB[k] + n2, 1e-12f));
        }
        redB[16 + wave] = s;
    }
    __syncthreads();
    if (tid < 16) {                              // cross-wave fold for A + sqrt
        float m = redA[tid];
        #pragma unroll
        for (int w = 1; w < 8; ++w) m = fminf(m, redA[w * 16 + tid]);
        const float2 p = pts[b * 16 + tid];
        redB[tid] = sqrtf(fmaxf(m + fmaf(p.x, p.x, p.y * p.y), 1e-12f));
    }
    __syncthreads();
    if (tid == 0) {                              // block partial, fixed order
        float t = 0.f;
        #pragma unroll
        for (int k = 0; k < 24; ++k) t += redB[k];
        partial[b] = t;                          // plain store, written once
    }
}

// ---------------- Kernel 2: sum 256 partials (plain store) -----------------
__global__ __launch_bounds__(256) void chamfer_sum(
    const float* __restrict__ partial, float* __restrict__ out)
{
    __shared__ float ssum[4];
    const int tid = threadIdx.x;
    float d = partial[tid];
    #pragma unroll
    for (int off = 32; off > 0; off >>= 1) d += __shfl_down(d, off, 64);
    const int lane = tid & 63, wave = tid >> 6;
    if (lane == 0) ssum[wave] = d;
    __syncthreads();
    if (tid == 0) out[0] = ssum[0] + ssum[1] + ssum[2] + ssum[3];
}

extern "C" void kernel_launch(void* const* d_in, const int* in_sizes, int n_in,
                              void* d_out, int out_size, void* d_ws, size_t ws_size,
                              hipStream_t stream) {
    const float2* pts  = (const float2*)d_in[0];            // circle 0 (offset 0)
    const float2* refs = ((const float2*)d_in[1]) + M_REF;  // last (=2nd) skeleton slice

    float* partial = (float*)d_ws;                          // [256] floats
    float* out = (float*)d_out;

    chamfer_fused<<<256, 512, 0, stream>>>(pts, refs, partial);
    chamfer_sum  <<<1, 256, 0, stream>>>(partial, out);
}